// Round 2
// baseline (87.088 us; speedup 1.0000x reference)
//
#include <hip/hip_runtime.h>
#include <math.h>

#define B_TOT 2048
#define IN_TOT 512
#define OUT_TOT 512
#define BK 32                 // k-tile
#define NT (IN_TOT / BK)      // 16 tiles
#define RPW 8                 // rows per wave
#define WAVES 4
#define RPB (RPW * WAVES)     // 32 rows per block
#define COLS 64               // output columns per block (= lanes)

__global__ __launch_bounds__(256, 2) void morph_kernel(
    const float* __restrict__ x,
    const float* __restrict__ wdil,
    const float* __restrict__ wero,
    float* __restrict__ out)
{
    // [2 buf][64 cols][32 k] floats, 8KB per array per buf
    __shared__ float wd_s[2][COLS * BK];
    __shared__ float we_s[2][COLS * BK];

    const int tid  = (int)threadIdx.x;
    const int lane = tid & 63;
    const int wav  = tid >> 6;

    const int col0 = (int)blockIdx.x * COLS;
    const int row0 = (int)blockIdx.y * RPB;
    // force wave-row base into SGPR so x addressing scalarizes (s_load)
    const int wrow = __builtin_amdgcn_readfirstlane(row0 + wav * RPW);

    const float* xp = x + (size_t)wrow * IN_TOT;

    // --- staging map: slot s = i*256 + tid ; col = s>>3 ; c_store = s&7 ---
    // LDS write is LINEAR (byte s*16); the bank-swizzle lives in the GLOBAL
    // source chunk: c_src = c_store ^ (col&7)   (m173 pattern)
    int soff[2];
#pragma unroll
    for (int i = 0; i < 2; ++i) {
        int s = i * 256 + tid;
        int c = s >> 3;
        int cs = (s & 7) ^ (c & 7);
        soff[i] = (col0 + c) * IN_TOT + cs * 4;   // float offset; + t*BK later
    }
    const int lw0 = tid * 4;          // float index of write slot 0
    const int lw1 = 1024 + tid * 4;   // write slot 1

    float dil[RPW], ero[RPW];
#pragma unroll
    for (int r = 0; r < RPW; ++r) { dil[r] = -INFINITY; ero[r] = INFINITY; }

    // prologue: stage tile 0 into buf 0
    {
        float4 a0 = *(const float4*)(wdil + soff[0]);
        float4 a1 = *(const float4*)(wdil + soff[1]);
        float4 b0 = *(const float4*)(wero + soff[0]);
        float4 b1 = *(const float4*)(wero + soff[1]);
        *(float4*)&wd_s[0][lw0] = a0;
        *(float4*)&wd_s[0][lw1] = a1;
        *(float4*)&we_s[0][lw0] = b0;
        *(float4*)&we_s[0][lw1] = b1;
    }
    __syncthreads();

    const int lbase = lane << 5;        // lane*32 floats (one col-row)
    const int lxor  = (lane & 7) << 2;  // float-index xor for bank spread

#pragma unroll 1
    for (int t = 0; t < NT; ++t) {
        const int buf = t & 1;
        const bool pf = (t + 1 < NT);
        float4 a0, a1, b0, b1;
        if (pf) {   // issue next tile's global loads early (T14 split)
            const int kb = (t + 1) * BK;
            a0 = *(const float4*)(wdil + soff[0] + kb);
            a1 = *(const float4*)(wdil + soff[1] + kb);
            b0 = *(const float4*)(wero + soff[0] + kb);
            b1 = *(const float4*)(wero + soff[1] + kb);
        }

        const float* wdp = &wd_s[buf][0];
        const float* wep = &we_s[buf][0];
        const float* xt  = xp + t * BK;

#pragma unroll
        for (int c = 0; c < 8; ++c) {
            const int wo = lbase + ((c << 2) ^ lxor);
            float4 wd4 = *(const float4*)(wdp + wo);   // ds_read_b128, conflict-free
            float4 we4 = *(const float4*)(wep + wo);
#pragma unroll
            for (int r = 0; r < RPW; ++r) {
                // wave-uniform x -> scalar load, SGPR operand in v_add/v_sub
                float4 xv = *(const float4*)(xt + r * IN_TOT + (c << 2));
                dil[r] = fmaxf(fmaxf(xv.x + wd4.x, xv.y + wd4.y),
                          fmaxf(fmaxf(xv.z + wd4.z, xv.w + wd4.w), dil[r]));
                ero[r] = fminf(fminf(xv.x - we4.x, xv.y - we4.y),
                          fminf(fminf(xv.z - we4.z, xv.w - we4.w), ero[r]));
            }
        }

        if (pf) {   // write-late into the other buffer
            const int nb = buf ^ 1;
            *(float4*)&wd_s[nb][lw0] = a0;
            *(float4*)&wd_s[nb][lw1] = a1;
            *(float4*)&we_s[nb][lw0] = b0;
            *(float4*)&we_s[nb][lw1] = b1;
        }
        __syncthreads();
    }

    float* op = out + (size_t)wrow * OUT_TOT + col0 + lane;
#pragma unroll
    for (int r = 0; r < RPW; ++r)
        op[r * OUT_TOT] = dil[r] + ero[r];
}

extern "C" void kernel_launch(void* const* d_in, const int* in_sizes, int n_in,
                              void* d_out, int out_size, void* d_ws, size_t ws_size,
                              hipStream_t stream)
{
    const float* x  = (const float*)d_in[0];
    const float* wd = (const float*)d_in[1];
    const float* we = (const float*)d_in[2];
    float* out = (float*)d_out;

    dim3 grid(OUT_TOT / COLS, B_TOT / RPB);   // (8, 64) = 512 blocks, 2/CU
    dim3 block(256);
    hipLaunchKernelGGL(morph_kernel, grid, block, 0, stream, x, wd, we, out);
}